// Round 1
// baseline (671.753 us; speedup 1.0000x reference)
//
#include <hip/hip_runtime.h>
#include <hip/hip_bf16.h>

typedef __attribute__((ext_vector_type(8))) short bf16x8;
typedef __attribute__((ext_vector_type(4))) float f32x4;

#define DEVI static __device__ __forceinline__

constexpr int BS = 4, SEQ = 2048, DIN = 4096, DOUT = 4096, RANK = 128;
constexpr int MTOT = BS * SEQ;  // 8192

DEVI unsigned short f2bf(float f) {
  __hip_bfloat16 h = __float2bfloat16(f);
  return __builtin_bit_cast(unsigned short, h);
}

// ---------------- prep kernels ----------------

__global__ void cast_bf16_kernel(const float* __restrict__ src,
                                 unsigned short* __restrict__ dst, int n4) {
  int i = blockIdx.x * blockDim.x + threadIdx.x;
  int stride = gridDim.x * blockDim.x;
  for (; i < n4; i += stride) {
    float4 v = reinterpret_cast<const float4*>(src)[i];
    ushort4 o;
    o.x = f2bf(v.x); o.y = f2bf(v.y); o.z = f2bf(v.z); o.w = f2bf(v.w);
    reinterpret_cast<ushort4*>(dst)[i] = o;
  }
}

// m[b][r][i] = bf16( 0.01*exp(64*log_lr[r][i]) * state[b][r][i] + w_bsp[r][i] )
__global__ void prep_m_kernel(const float* __restrict__ log_lr,
                              const float* __restrict__ state,
                              const float* __restrict__ w_bsp,
                              unsigned short* __restrict__ m_bf) {
  const int n4 = BS * RANK * DIN / 4;
  int i = blockIdx.x * blockDim.x + threadIdx.x;
  int stride = gridDim.x * blockDim.x;
  for (; i < n4; i += stride) {
    int ri4 = (i * 4) % (RANK * DIN) / 4;
    float4 ll = reinterpret_cast<const float4*>(log_lr)[ri4];
    float4 wb = reinterpret_cast<const float4*>(w_bsp)[ri4];
    float4 st = reinterpret_cast<const float4*>(state)[i];
    ushort4 o;
    o.x = f2bf(0.01f * __expf(ll.x * 64.0f) * st.x + wb.x);
    o.y = f2bf(0.01f * __expf(ll.y * 64.0f) * st.y + wb.y);
    o.z = f2bf(0.01f * __expf(ll.z * 64.0f) * st.z + wb.z);
    o.w = f2bf(0.01f * __expf(ll.w * 64.0f) * st.w + wb.w);
    reinterpret_cast<ushort4*>(m_bf)[i] = o;
  }
}

// ---------------- GEMM building blocks ----------------

DEVI void gload16(const void* g, void* l) {
  __builtin_amdgcn_global_load_lds(
      (const __attribute__((address_space(1))) void*)g,
      (__attribute__((address_space(3))) void*)l, 16, 0, 0);
}

// Stage a [ROWS][32] bf16 tile (row stride ldBytes in global) into linear LDS
// [ROWS][64B]. 1KB chunk = 16 rows; dest is wave-uniform base + lane*16.
template <int ROWS>
DEVI void stage_tile(const char* gbase, int ldBytes, char* lds) {
  const int lane = threadIdx.x & 63;
  const int wave = threadIdx.x >> 6;
  constexpr int CHUNKS = ROWS / 16;   // 1KB chunks
  constexpr int CPW = CHUNKS / 4;     // 4 waves
  const int colByte = (lane & 3) << 4;
  const int rowInChunk = lane >> 2;
#pragma unroll
  for (int c = 0; c < CPW; ++c) {
    int chunk = wave * CPW + c;
    int row = chunk * 16 + rowInChunk;
    gload16(gbase + (size_t)row * ldBytes + colByte, lds + chunk * 1024);
  }
}

// 4 waves in 2x2; each wave computes (F*16)x(F*16) via 16x16x32 MFMA.
// LDS tiles are [*][32] bf16, rows = output rows (A) / output cols (B).
template <int F>
DEVI void compute_tile(const char* lA, const char* lB, f32x4 (&acc)[F][F]) {
  const int lane = threadIdx.x & 63;
  const int wave = threadIdx.x >> 6;
  const int wr = wave >> 1, wc = wave & 1;
  const int kByte = (lane >> 4) * 16;   // 8 bf16 along k per lane group
  const int rsel = lane & 15;
  bf16x8 a[F], b[F];
#pragma unroll
  for (int mi = 0; mi < F; ++mi) {
    int row = wr * (F * 16) + mi * 16 + rsel;
    a[mi] = *reinterpret_cast<const bf16x8*>(lA + row * 64 + kByte);
  }
#pragma unroll
  for (int ni = 0; ni < F; ++ni) {
    int row = wc * (F * 16) + ni * 16 + rsel;
    b[ni] = *reinterpret_cast<const bf16x8*>(lB + row * 64 + kByte);
  }
#pragma unroll
  for (int mi = 0; mi < F; ++mi)
#pragma unroll
    for (int ni = 0; ni < F; ++ni)
      acc[mi][ni] =
          __builtin_amdgcn_mfma_f32_16x16x32_bf16(a[mi], b[ni], acc[mi][ni], 0, 0, 0);
}

// ---------------- z GEMM: z[m][r] = sum_i x[m][i]*mB[r][i] ----------------
// grid: (MTOT/64) * (RANK/64) = 128*2 = 256 blocks, 256 threads.
__global__ __launch_bounds__(256) void z_gemm_kernel(
    const unsigned short* __restrict__ xbf, const unsigned short* __restrict__ mbf,
    unsigned short* __restrict__ zbf) {
  int mt = blockIdx.x >> 1, nt = blockIdx.x & 1;
  int row0 = mt * 64;
  int batch = row0 >> 11;  // /SEQ
  const char* xb = (const char*)(xbf + (size_t)row0 * DIN);
  const char* mb = (const char*)(mbf + ((size_t)batch * RANK + nt * 64) * DIN);
  __shared__ __align__(16) char lA[2][64 * 64];
  __shared__ __align__(16) char lB[2][64 * 64];
  f32x4 acc[2][2] = {};
  constexpr int NT = DIN / 32;  // 128
  stage_tile<64>(xb, DIN * 2, lA[0]);
  stage_tile<64>(mb, DIN * 2, lB[0]);
  for (int t = 0; t < NT; ++t) {
    __syncthreads();
    if (t + 1 < NT) {
      stage_tile<64>(xb + (t + 1) * 64, DIN * 2, lA[(t + 1) & 1]);
      stage_tile<64>(mb + (t + 1) * 64, DIN * 2, lB[(t + 1) & 1]);
    }
    compute_tile<2>(lA[t & 1], lB[t & 1], acc);
  }
  const int lane = threadIdx.x & 63;
  const int wave = threadIdx.x >> 6;
  const int wr = wave >> 1, wc = wave & 1;
#pragma unroll
  for (int mi = 0; mi < 2; ++mi)
#pragma unroll
    for (int ni = 0; ni < 2; ++ni) {
      int c = nt * 64 + wc * 32 + ni * 16 + (lane & 15);
      int r0 = row0 + wr * 32 + mi * 16 + (lane >> 4) * 4;
#pragma unroll
      for (int j = 0; j < 4; ++j)
        zbf[(size_t)(r0 + j) * RANK + c] = f2bf(acc[mi][ni][j]);
    }
}

// ---------------- main GEMM ----------------
// y[m][o] = sum_i x[m][i]*wl[o][i] + sum_r z[m][r]*wo[o][r] + b[o]
// grid: (8192/128)*(4096/128) = 64*32 = 2048 blocks, 256 threads.
__global__ __launch_bounds__(256) void main_gemm_kernel(
    const unsigned short* __restrict__ xbf, const unsigned short* __restrict__ wlbf,
    const unsigned short* __restrict__ zbf, const unsigned short* __restrict__ wobf,
    const float* __restrict__ b_lin, float* __restrict__ out) {
  int bid = blockIdx.x;
  // XCD-bijective swizzle (2048 % 8 == 0): XCD x gets a contiguous tile chunk.
  int swz = (bid & 7) * 256 + (bid >> 3);
  int mt = swz >> 5, nt = swz & 31;
  int row0 = mt * 128, col0 = nt * 128;

  const char* xb = (const char*)(xbf + (size_t)row0 * DIN);
  const char* wb = (const char*)(wlbf + (size_t)col0 * DIN);
  const char* zb = (const char*)(zbf + (size_t)row0 * RANK);
  const char* ob = (const char*)(wobf + (size_t)col0 * RANK);

  __shared__ __align__(16) char lA[2][128 * 64];
  __shared__ __align__(16) char lB[2][128 * 64];
  f32x4 acc[4][4] = {};

  constexpr int NK1 = DIN / 32;   // 128 k-tiles of x·wl
  constexpr int NK2 = RANK / 32;  // 4 k-tiles of z·wo
  constexpr int NT = NK1 + NK2;

  stage_tile<128>(xb, DIN * 2, lA[0]);
  stage_tile<128>(wb, DIN * 2, lB[0]);

  for (int t = 0; t < NT; ++t) {
    __syncthreads();
    int nx = t + 1;
    if (nx < NT) {
      char* dA = lA[nx & 1];
      char* dB = lB[nx & 1];
      if (nx < NK1) {
        stage_tile<128>(xb + nx * 64, DIN * 2, dA);
        stage_tile<128>(wb + nx * 64, DIN * 2, dB);
      } else {
        int kb = (nx - NK1) * 64;
        stage_tile<128>(zb + kb, RANK * 2, dA);
        stage_tile<128>(ob + kb, RANK * 2, dB);
      }
    }
    compute_tile<4>(lA[t & 1], lB[t & 1], acc);
  }

  const int lane = threadIdx.x & 63;
  const int wave = threadIdx.x >> 6;
  const int wr = wave >> 1, wc = wave & 1;
  const int rbase = row0 + wr * 64 + (lane >> 4) * 4;
  const int cbase = col0 + wc * 64 + (lane & 15);
#pragma unroll
  for (int mi = 0; mi < 4; ++mi)
#pragma unroll
    for (int ni = 0; ni < 4; ++ni) {
      int c = cbase + ni * 16;
      float bv = b_lin[c];
      int r = rbase + mi * 16;
#pragma unroll
      for (int j = 0; j < 4; ++j)
        out[(size_t)(r + j) * DOUT + c] = acc[mi][ni][j] + bv;
    }
}

// ---------------- launch ----------------

extern "C" void kernel_launch(void* const* d_in, const int* in_sizes, int n_in,
                              void* d_out, int out_size, void* d_ws, size_t ws_size,
                              hipStream_t stream) {
  const float* x = (const float*)d_in[0];
  const float* log_lr = (const float*)d_in[1];
  const float* state = (const float*)d_in[2];
  // d_in[3] = grad_buffer (unused in forward)
  const float* w_bsp = (const float*)d_in[4];
  const float* w_out = (const float*)d_in[5];
  const float* w_lin = (const float*)d_in[6];
  const float* b_lin = (const float*)d_in[7];
  float* out = (float*)d_out;

  // workspace layout (bf16), total ~103 MB
  unsigned short* xbf = (unsigned short*)d_ws;
  unsigned short* wlbf = xbf + (size_t)MTOT * DIN;          // 67108864 B
  unsigned short* wobf = wlbf + (size_t)DOUT * DIN;         // +33554432 B
  unsigned short* mbf = wobf + (size_t)DOUT * RANK;         // +1048576 B
  unsigned short* zbf = mbf + (size_t)BS * RANK * DIN;      // +4194304 B
                                                            // +2097152 B

  cast_bf16_kernel<<<2048, 256, 0, stream>>>(x, xbf, MTOT * DIN / 4);
  cast_bf16_kernel<<<2048, 256, 0, stream>>>(w_lin, wlbf, DOUT * DIN / 4);
  cast_bf16_kernel<<<512, 256, 0, stream>>>(w_out, wobf, DOUT * RANK / 4);
  prep_m_kernel<<<2048, 256, 0, stream>>>(log_lr, state, w_bsp, mbf);
  z_gemm_kernel<<<256, 256, 0, stream>>>(xbf, mbf, zbf);
  main_gemm_kernel<<<2048, 256, 0, stream>>>(xbf, wlbf, zbf, wobf, b_lin, out);
}

// Round 3
// 563.191 us; speedup vs baseline: 1.1928x; 1.1928x over previous
//
#include <hip/hip_runtime.h>
#include <hip/hip_bf16.h>

typedef __attribute__((ext_vector_type(8))) short bf16x8;
typedef __attribute__((ext_vector_type(4))) float f32x4;

#define DEVI static __device__ __forceinline__

constexpr int BS = 4, SEQ = 2048, DIN = 4096, DOUT = 4096, RANK = 128;
constexpr int MTOT = BS * SEQ;  // 8192

DEVI unsigned short f2bf(float f) {
  __hip_bfloat16 h = __float2bfloat16(f);
  return __builtin_bit_cast(unsigned short, h);
}

// ---------------- prep kernels ----------------

__global__ void cast_bf16_kernel(const float* __restrict__ src,
                                 unsigned short* __restrict__ dst, int n4) {
  int i = blockIdx.x * blockDim.x + threadIdx.x;
  int stride = gridDim.x * blockDim.x;
  for (; i < n4; i += stride) {
    float4 v = reinterpret_cast<const float4*>(src)[i];
    ushort4 o;
    o.x = f2bf(v.x); o.y = f2bf(v.y); o.z = f2bf(v.z); o.w = f2bf(v.w);
    reinterpret_cast<ushort4*>(dst)[i] = o;
  }
}

__global__ void prep_m_kernel(const float* __restrict__ log_lr,
                              const float* __restrict__ state,
                              const float* __restrict__ w_bsp,
                              unsigned short* __restrict__ m_bf) {
  const int n4 = BS * RANK * DIN / 4;
  int i = blockIdx.x * blockDim.x + threadIdx.x;
  int stride = gridDim.x * blockDim.x;
  for (; i < n4; i += stride) {
    int ri4 = (i * 4) % (RANK * DIN) / 4;
    float4 ll = reinterpret_cast<const float4*>(log_lr)[ri4];
    float4 wb = reinterpret_cast<const float4*>(w_bsp)[ri4];
    float4 st = reinterpret_cast<const float4*>(state)[i];
    ushort4 o;
    o.x = f2bf(0.01f * __expf(ll.x * 64.0f) * st.x + wb.x);
    o.y = f2bf(0.01f * __expf(ll.y * 64.0f) * st.y + wb.y);
    o.z = f2bf(0.01f * __expf(ll.z * 64.0f) * st.z + wb.z);
    o.w = f2bf(0.01f * __expf(ll.w * 64.0f) * st.w + wb.w);
    reinterpret_cast<ushort4*>(m_bf)[i] = o;
  }
}

// ---------------- shared building blocks ----------------

DEVI void gload16(const void* g, void* l) {
  __builtin_amdgcn_global_load_lds(
      (const __attribute__((address_space(1))) void*)g,
      (__attribute__((address_space(3))) void*)l, 16, 0, 0);
}

// Linear (unswizzled) staging for the small z kernel: [ROWS][32] bf16 tile.
template <int ROWS>
DEVI void stage_tile(const char* gbase, int ldBytes, char* lds) {
  const int lane = threadIdx.x & 63;
  const int wave = threadIdx.x >> 6;
  constexpr int CHUNKS = ROWS / 16;
  constexpr int CPW = CHUNKS / 4;
  const int colByte = (lane & 3) << 4;
  const int rowInChunk = lane >> 2;
#pragma unroll
  for (int c = 0; c < CPW; ++c) {
    int chunk = wave * CPW + c;
    int row = chunk * 16 + rowInChunk;
    gload16(gbase + (size_t)row * ldBytes + colByte, lds + chunk * 1024);
  }
}

template <int F>
DEVI void compute_tile(const char* lA, const char* lB, f32x4 (&acc)[F][F]) {
  const int lane = threadIdx.x & 63;
  const int wave = threadIdx.x >> 6;
  const int wr = wave >> 1, wc = wave & 1;
  const int kByte = (lane >> 4) * 16;
  const int rsel = lane & 15;
  bf16x8 a[F], b[F];
#pragma unroll
  for (int mi = 0; mi < F; ++mi) {
    int row = wr * (F * 16) + mi * 16 + rsel;
    a[mi] = *reinterpret_cast<const bf16x8*>(lA + row * 64 + kByte);
  }
#pragma unroll
  for (int ni = 0; ni < F; ++ni) {
    int row = wc * (F * 16) + ni * 16 + rsel;
    b[ni] = *reinterpret_cast<const bf16x8*>(lB + row * 64 + kByte);
  }
#pragma unroll
  for (int mi = 0; mi < F; ++mi)
#pragma unroll
    for (int ni = 0; ni < F; ++ni)
      acc[mi][ni] =
          __builtin_amdgcn_mfma_f32_16x16x32_bf16(a[mi], b[ni], acc[mi][ni], 0, 0, 0);
}

// ---------------- z GEMM (split-K): zpart[ks][m][r] = partial sums ----------------
// grid: 128 mt * 2 nt * KS, 256 threads. bid = ((mt*2+nt)*KS)+ks
template <int KS>
__global__ __launch_bounds__(256) void z_gemm_splitk(
    const unsigned short* __restrict__ xbf, const unsigned short* __restrict__ mbf,
    float* __restrict__ zpart) {
  int bid = blockIdx.x;
  int ksl = bid & (KS - 1);
  int rest = bid / KS;
  int nt = rest & 1, mt = rest >> 1;
  int row0 = mt * 64;
  int batch = row0 >> 11;
  int kbase = ksl * (DIN / KS);
  const char* xb = (const char*)(xbf + (size_t)row0 * DIN + kbase);
  const char* mb = (const char*)(mbf + ((size_t)batch * RANK + nt * 64) * DIN + kbase);
  __shared__ __align__(16) char lA[2][64 * 64];
  __shared__ __align__(16) char lB[2][64 * 64];
  f32x4 acc[2][2] = {};
  constexpr int NT = DIN / KS / 32;
  stage_tile<64>(xb, DIN * 2, lA[0]);
  stage_tile<64>(mb, DIN * 2, lB[0]);
  for (int t = 0; t < NT; ++t) {
    __syncthreads();
    if (t + 1 < NT) {
      stage_tile<64>(xb + (t + 1) * 64, DIN * 2, lA[(t + 1) & 1]);
      stage_tile<64>(mb + (t + 1) * 64, DIN * 2, lB[(t + 1) & 1]);
    }
    compute_tile<2>(lA[t & 1], lB[t & 1], acc);
  }
  const int lane = threadIdx.x & 63;
  const int wave = threadIdx.x >> 6;
  const int wr = wave >> 1, wc = wave & 1;
#pragma unroll
  for (int mi = 0; mi < 2; ++mi)
#pragma unroll
    for (int ni = 0; ni < 2; ++ni) {
      int c = nt * 64 + wc * 32 + ni * 16 + (lane & 15);
      int r0 = row0 + wr * 32 + mi * 16 + (lane >> 4) * 4;
#pragma unroll
      for (int j = 0; j < 4; ++j)
        zpart[((size_t)ksl * MTOT + r0 + j) * RANK + c] = acc[mi][ni][j];
    }
}

template <int KS>
__global__ void z_reduce_kernel(const float* __restrict__ zpart,
                                unsigned short* __restrict__ zbf) {
  const int n4 = MTOT * RANK / 4;
  int i = blockIdx.x * blockDim.x + threadIdx.x;
  if (i >= n4) return;
  float4 s = reinterpret_cast<const float4*>(zpart)[i];
#pragma unroll
  for (int k = 1; k < KS; ++k) {
    float4 v = reinterpret_cast<const float4*>(zpart)[(size_t)k * n4 + i];
    s.x += v.x; s.y += v.y; s.z += v.z; s.w += v.w;
  }
  ushort4 o;
  o.x = f2bf(s.x); o.y = f2bf(s.y); o.z = f2bf(s.z); o.w = f2bf(s.w);
  reinterpret_cast<ushort4*>(zbf)[i] = o;
}

// fallback (no split-K) — round-1 kernel
__global__ __launch_bounds__(256) void z_gemm_kernel(
    const unsigned short* __restrict__ xbf, const unsigned short* __restrict__ mbf,
    unsigned short* __restrict__ zbf) {
  int mt = blockIdx.x >> 1, nt = blockIdx.x & 1;
  int row0 = mt * 64;
  int batch = row0 >> 11;
  const char* xb = (const char*)(xbf + (size_t)row0 * DIN);
  const char* mb = (const char*)(mbf + ((size_t)batch * RANK + nt * 64) * DIN);
  __shared__ __align__(16) char lA[2][64 * 64];
  __shared__ __align__(16) char lB[2][64 * 64];
  f32x4 acc[2][2] = {};
  constexpr int NT = DIN / 32;
  stage_tile<64>(xb, DIN * 2, lA[0]);
  stage_tile<64>(mb, DIN * 2, lB[0]);
  for (int t = 0; t < NT; ++t) {
    __syncthreads();
    if (t + 1 < NT) {
      stage_tile<64>(xb + (t + 1) * 64, DIN * 2, lA[(t + 1) & 1]);
      stage_tile<64>(mb + (t + 1) * 64, DIN * 2, lB[(t + 1) & 1]);
    }
    compute_tile<2>(lA[t & 1], lB[t & 1], acc);
  }
  const int lane = threadIdx.x & 63;
  const int wave = threadIdx.x >> 6;
  const int wr = wave >> 1, wc = wave & 1;
#pragma unroll
  for (int mi = 0; mi < 2; ++mi)
#pragma unroll
    for (int ni = 0; ni < 2; ++ni) {
      int c = nt * 64 + wc * 32 + ni * 16 + (lane & 15);
      int r0 = row0 + wr * 32 + mi * 16 + (lane >> 4) * 4;
#pragma unroll
      for (int j = 0; j < 4; ++j)
        zbf[(size_t)(r0 + j) * RANK + c] = f2bf(acc[mi][ni][j]);
    }
}

// ---------------- main GEMM: 256x256 tile, BK=64, 8 waves, 8-phase ----------------
// y[m][o] = sum_i x[m][i]*wl[o][i] + sum_r z[m][r]*wo[o][r] + b[o]
// K-tiles: 0..63 from x/wl (BK=64 of DIN), 64..65 from z/wo (BK=64 of RANK).
// LDS 128 KiB: A[d][half][128][64]bf16 swizzled, B same at +64KiB.
// Swizzle: element (r,c2B) at byte r*128 + ((c*2) ^ ((r&7)<<4)); applied on the
// global SOURCE during global_load_lds staging (linear LDS dest) and on reads.
// Schedule per iter (tiles t,t+1; buf0=even, buf1=odd), 1 half staged/phase:
//   p1:A(t+1)h0->1  p2:A(t+1)h1->1  p3:B(t+2)h0->0  p4:B(t+2)h1->0
//   p5:A(t+2)h0->0  p6:A(t+2)h1->0  p7:B(t+3)h0->1  p8:B(t+3)h1->1
// vmcnt(4) (= 2 half-tiles in flight) before every closing barrier keeps every
// stage->consume distance >= 3 phases drained. Stage indices clamp to 65 so the
// counts stay exact through the tail (clamped stages only hit dead buffers).

struct MainCtx {
  const char* lds;
  int wr, wc, rsel, kgrp, xorv;
};

DEVI const bf16x8* lda_frag(const MainCtx& c, int d, int mi, int ks) {
  int col = ((ks * 64) + c.kgrp * 16) ^ c.xorv;
  return reinterpret_cast<const bf16x8*>(
      c.lds + d * 32768 + c.wr * 16384 + mi * 2048 + c.rsel * 128 + col);
}
DEVI const bf16x8* ldb_frag(const MainCtx& c, int d, int ni, int ks) {
  int col = ((ks * 64) + c.kgrp * 16) ^ c.xorv;
  return reinterpret_cast<const bf16x8*>(
      c.lds + 65536 + d * 32768 + (c.wc >> 1) * 16384 + (c.wc & 1) * 8192 +
      ni * 2048 + c.rsel * 128 + col);
}

template <int D, int Q, class STG>
DEVI void phase_body(const MainCtx& c, f32x4 (&acc)[8][4], bf16x8 (&bfr)[4][2],
                     STG&& stg) {
  bf16x8 a00 = *lda_frag(c, D, 2 * Q, 0);
  bf16x8 a01 = *lda_frag(c, D, 2 * Q, 1);
  bf16x8 a10 = *lda_frag(c, D, 2 * Q + 1, 0);
  bf16x8 a11 = *lda_frag(c, D, 2 * Q + 1, 1);
  if (Q == 0) {
#pragma unroll
    for (int ni = 0; ni < 4; ++ni) {
      bfr[ni][0] = *ldb_frag(c, D, ni, 0);
      bfr[ni][1] = *ldb_frag(c, D, ni, 1);
    }
  }
  stg();
  __builtin_amdgcn_s_barrier();
  asm volatile("s_waitcnt lgkmcnt(0)" ::: "memory");
  __builtin_amdgcn_s_setprio(1);
#pragma unroll
  for (int ni = 0; ni < 4; ++ni) {
    acc[2 * Q][ni] = __builtin_amdgcn_mfma_f32_16x16x32_bf16(a00, bfr[ni][0], acc[2 * Q][ni], 0, 0, 0);
    acc[2 * Q + 1][ni] = __builtin_amdgcn_mfma_f32_16x16x32_bf16(a10, bfr[ni][0], acc[2 * Q + 1][ni], 0, 0, 0);
  }
#pragma unroll
  for (int ni = 0; ni < 4; ++ni) {
    acc[2 * Q][ni] = __builtin_amdgcn_mfma_f32_16x16x32_bf16(a01, bfr[ni][1], acc[2 * Q][ni], 0, 0, 0);
    acc[2 * Q + 1][ni] = __builtin_amdgcn_mfma_f32_16x16x32_bf16(a11, bfr[ni][1], acc[2 * Q + 1][ni], 0, 0, 0);
  }
  __builtin_amdgcn_s_setprio(0);
  asm volatile("s_waitcnt vmcnt(4)" ::: "memory");
  __builtin_amdgcn_s_barrier();
}

__global__ __launch_bounds__(512, 2) void main_gemm_8p(
    const unsigned short* __restrict__ xbf, const unsigned short* __restrict__ wlbf,
    const unsigned short* __restrict__ zbf, const unsigned short* __restrict__ wobf,
    const float* __restrict__ b_lin, float* __restrict__ out) {
  __shared__ __align__(16) char lds[131072];

  const int tid = threadIdx.x;
  const int lane = tid & 63, wave = tid >> 6;

  int bid = blockIdx.x;                      // 512 blocks, 512%8==0
  int swz = (bid & 7) * 64 + (bid >> 3);     // bijective XCD swizzle
  int mt = swz >> 4, nt = swz & 15;
  const int row0 = mt * 256, col0 = nt * 256;

  const char* xb = (const char*)(xbf + (size_t)row0 * DIN);
  const char* wb = (const char*)(wlbf + (size_t)col0 * DIN);
  const char* zb = (const char*)(zbf + (size_t)row0 * RANK);
  const char* ob = (const char*)(wobf + (size_t)col0 * RANK);

  // staging lane constants: chunk=wave*2+c (1KB = 8 rows of 128B), per-thread 2 loads
  const int srow8 = lane >> 3;                          // row & 7
  const int scolS = ((lane & 7) ^ srow8) << 4;          // pre-swizzled source col byte
  const int chunk0 = wave * 2;

  auto stage = [&](const char* gbase, int ld, int ldsOff) {
    gload16(gbase + (size_t)(chunk0 * 8 + srow8) * ld + scolS,
            (void*)&lds[ldsOff + chunk0 * 1024]);
    gload16(gbase + (size_t)(chunk0 * 8 + 8 + srow8) * ld + scolS,
            (void*)&lds[ldsOff + chunk0 * 1024 + 1024]);
  };
  auto stageA = [&](int k, int h, int d) {
    const char* g; int ld;
    if (k < 64) { g = xb + (size_t)h * 128 * (DIN * 2) + (size_t)k * 128; ld = DIN * 2; }
    else        { g = zb + (size_t)h * 128 * (RANK * 2) + (size_t)(k - 64) * 128; ld = RANK * 2; }
    stage(g, ld, d * 32768 + h * 16384);
  };
  auto stageB = [&](int k, int h, int d) {
    const char* g; int ld;
    if (k < 64) { g = wb + (size_t)h * 128 * (DIN * 2) + (size_t)k * 128; ld = DIN * 2; }
    else        { g = ob + (size_t)h * 128 * (RANK * 2) + (size_t)(k - 64) * 128; ld = RANK * 2; }
    stage(g, ld, 65536 + d * 32768 + h * 16384);
  };

  MainCtx c{lds, wave >> 2, wave & 3, lane & 15, lane >> 4, (lane & 7) << 4};

  f32x4 acc[8][4] = {};
  bf16x8 bfr[4][2];

  // prologue: tile0 (A,B) + B(1); leave B(1)'s 4 loads in flight
  stageB(0, 0, 0); stageB(0, 1, 0);
  stageA(0, 0, 0); stageA(0, 1, 0);
  stageB(1, 0, 1); stageB(1, 1, 1);
  asm volatile("s_waitcnt vmcnt(4)" ::: "memory");
  __builtin_amdgcn_s_barrier();

  constexpr int NKT = 66;  // 64 (x/wl) + 2 (z/wo)
  for (int j = 0; j < NKT / 2; ++j) {
    int t = 2 * j;
    int kA1 = (t + 1 < NKT - 1) ? t + 1 : NKT - 1;
    int kN2 = (t + 2 < NKT - 1) ? t + 2 : NKT - 1;
    int kB3 = (t + 3 < NKT - 1) ? t + 3 : NKT - 1;
    phase_body<0, 0>(c, acc, bfr, [&] { stageA(kA1, 0, 1); });
    phase_body<0, 1>(c, acc, bfr, [&] { stageA(kA1, 1, 1); });
    phase_body<0, 2>(c, acc, bfr, [&] { stageB(kN2, 0, 0); });
    phase_body<0, 3>(c, acc, bfr, [&] { stageB(kN2, 1, 0); });
    phase_body<1, 0>(c, acc, bfr, [&] { stageA(kN2, 0, 0); });
    phase_body<1, 1>(c, acc, bfr, [&] { stageA(kN2, 1, 0); });
    phase_body<1, 2>(c, acc, bfr, [&] { stageB(kB3, 0, 1); });
    phase_body<1, 3>(c, acc, bfr, [&] { stageB(kB3, 1, 1); });
  }
  asm volatile("s_waitcnt vmcnt(0)" ::: "memory");

  // epilogue
  const int wr = wave >> 2, wc = wave & 3;
  const int rbase = row0 + wr * 128 + (lane >> 4) * 4;
  const int cbase = col0 + wc * 64 + (lane & 15);
#pragma unroll
  for (int mi = 0; mi < 8; ++mi)
#pragma unroll
    for (int ni = 0; ni < 4; ++ni) {
      int cc = cbase + ni * 16;
      float bv = b_lin[cc];
      int r = rbase + mi * 16;
#pragma unroll
      for (int j2 = 0; j2 < 4; ++j2)
        out[(size_t)(r + j2) * DOUT + cc] = acc[mi][ni][j2] + bv;
    }
}

// ---------------- launch ----------------

extern "C" void kernel_launch(void* const* d_in, const int* in_sizes, int n_in,
                              void* d_out, int out_size, void* d_ws, size_t ws_size,
                              hipStream_t stream) {
  const float* x = (const float*)d_in[0];
  const float* log_lr = (const float*)d_in[1];
  const float* state = (const float*)d_in[2];
  const float* w_bsp = (const float*)d_in[4];
  const float* w_out = (const float*)d_in[5];
  const float* w_lin = (const float*)d_in[6];
  const float* b_lin = (const float*)d_in[7];
  float* out = (float*)d_out;

  unsigned short* xbf = (unsigned short*)d_ws;              // 67108864 B
  unsigned short* wlbf = xbf + (size_t)MTOT * DIN;          // 33554432 B
  unsigned short* wobf = wlbf + (size_t)DOUT * DIN;         // 1048576 B
  unsigned short* mbf = wobf + (size_t)DOUT * RANK;         // 4194304 B
  unsigned short* zbf = mbf + (size_t)BS * RANK * DIN;      // 2097152 B
  float* zpart = (float*)(zbf + (size_t)MTOT * RANK);       // 16777216 B
  const size_t need_split = 108003328 + 16777216;

  cast_bf16_kernel<<<2048, 256, 0, stream>>>(x, xbf, MTOT * DIN / 4);
  cast_bf16_kernel<<<2048, 256, 0, stream>>>(w_lin, wlbf, DOUT * DIN / 4);
  cast_bf16_kernel<<<512, 256, 0, stream>>>(w_out, wobf, DOUT * RANK / 4);
  prep_m_kernel<<<2048, 256, 0, stream>>>(log_lr, state, w_bsp, mbf);

  if (ws_size >= need_split) {
    z_gemm_splitk<4><<<1024, 256, 0, stream>>>(xbf, mbf, zpart);
    z_reduce_kernel<4><<<1024, 256, 0, stream>>>(zpart, zbf);
  } else {
    z_gemm_kernel<<<256, 256, 0, stream>>>(xbf, mbf, zbf);
  }

  main_gemm_8p<<<512, 512, 0, stream>>>(xbf, wlbf, zbf, wobf, b_lin, out);
}

// Round 4
// 554.447 us; speedup vs baseline: 1.2116x; 1.0158x over previous
//
#include <hip/hip_runtime.h>
#include <hip/hip_bf16.h>

typedef __attribute__((ext_vector_type(8))) short bf16x8;
typedef __attribute__((ext_vector_type(4))) float f32x4;

#define DEVI static __device__ __forceinline__

constexpr int BS = 4, SEQ = 2048, DIN = 4096, DOUT = 4096, RANK = 128;
constexpr int MTOT = BS * SEQ;  // 8192

DEVI unsigned short f2bf(float f) {
  __hip_bfloat16 h = __float2bfloat16(f);
  return __builtin_bit_cast(unsigned short, h);
}

// ---------------- prep kernels ----------------

__global__ void cast_bf16_kernel(const float* __restrict__ src,
                                 unsigned short* __restrict__ dst, int n4) {
  int i = blockIdx.x * blockDim.x + threadIdx.x;
  int stride = gridDim.x * blockDim.x;
  for (; i < n4; i += stride) {
    float4 v = reinterpret_cast<const float4*>(src)[i];
    ushort4 o;
    o.x = f2bf(v.x); o.y = f2bf(v.y); o.z = f2bf(v.z); o.w = f2bf(v.w);
    reinterpret_cast<ushort4*>(dst)[i] = o;
  }
}

__global__ void prep_m_kernel(const float* __restrict__ log_lr,
                              const float* __restrict__ state,
                              const float* __restrict__ w_bsp,
                              unsigned short* __restrict__ m_bf) {
  const int n4 = BS * RANK * DIN / 4;
  int i = blockIdx.x * blockDim.x + threadIdx.x;
  int stride = gridDim.x * blockDim.x;
  for (; i < n4; i += stride) {
    int ri4 = (i * 4) % (RANK * DIN) / 4;
    float4 ll = reinterpret_cast<const float4*>(log_lr)[ri4];
    float4 wb = reinterpret_cast<const float4*>(w_bsp)[ri4];
    float4 st = reinterpret_cast<const float4*>(state)[i];
    ushort4 o;
    o.x = f2bf(0.01f * __expf(ll.x * 64.0f) * st.x + wb.x);
    o.y = f2bf(0.01f * __expf(ll.y * 64.0f) * st.y + wb.y);
    o.z = f2bf(0.01f * __expf(ll.z * 64.0f) * st.z + wb.z);
    o.w = f2bf(0.01f * __expf(ll.w * 64.0f) * st.w + wb.w);
    reinterpret_cast<ushort4*>(m_bf)[i] = o;
  }
}

// ---------------- shared building blocks ----------------

DEVI void gload16(const void* g, void* l) {
  __builtin_amdgcn_global_load_lds(
      (const __attribute__((address_space(1))) void*)g,
      (__attribute__((address_space(3))) void*)l, 16, 0, 0);
}

// Linear (unswizzled) staging for the small z kernel: [ROWS][32] bf16 tile.
template <int ROWS>
DEVI void stage_tile(const char* gbase, int ldBytes, char* lds) {
  const int lane = threadIdx.x & 63;
  const int wave = threadIdx.x >> 6;
  constexpr int CHUNKS = ROWS / 16;
  constexpr int CPW = CHUNKS / 4;
  const int colByte = (lane & 3) << 4;
  const int rowInChunk = lane >> 2;
#pragma unroll
  for (int c = 0; c < CPW; ++c) {
    int chunk = wave * CPW + c;
    int row = chunk * 16 + rowInChunk;
    gload16(gbase + (size_t)row * ldBytes + colByte, lds + chunk * 1024);
  }
}

template <int F>
DEVI void compute_tile(const char* lA, const char* lB, f32x4 (&acc)[F][F]) {
  const int lane = threadIdx.x & 63;
  const int wave = threadIdx.x >> 6;
  const int wr = wave >> 1, wc = wave & 1;
  const int kByte = (lane >> 4) * 16;
  const int rsel = lane & 15;
  bf16x8 a[F], b[F];
#pragma unroll
  for (int mi = 0; mi < F; ++mi) {
    int row = wr * (F * 16) + mi * 16 + rsel;
    a[mi] = *reinterpret_cast<const bf16x8*>(lA + row * 64 + kByte);
  }
#pragma unroll
  for (int ni = 0; ni < F; ++ni) {
    int row = wc * (F * 16) + ni * 16 + rsel;
    b[ni] = *reinterpret_cast<const bf16x8*>(lB + row * 64 + kByte);
  }
#pragma unroll
  for (int mi = 0; mi < F; ++mi)
#pragma unroll
    for (int ni = 0; ni < F; ++ni)
      acc[mi][ni] =
          __builtin_amdgcn_mfma_f32_16x16x32_bf16(a[mi], b[ni], acc[mi][ni], 0, 0, 0);
}

// ---------------- z GEMM (split-K): zpart[ks][m][r] = partial sums ----------------
template <int KS>
__global__ __launch_bounds__(256) void z_gemm_splitk(
    const unsigned short* __restrict__ xbf, const unsigned short* __restrict__ mbf,
    float* __restrict__ zpart) {
  int bid = blockIdx.x;
  int ksl = bid & (KS - 1);
  int rest = bid / KS;
  int nt = rest & 1, mt = rest >> 1;
  int row0 = mt * 64;
  int batch = row0 >> 11;
  int kbase = ksl * (DIN / KS);
  const char* xb = (const char*)(xbf + (size_t)row0 * DIN + kbase);
  const char* mb = (const char*)(mbf + ((size_t)batch * RANK + nt * 64) * DIN + kbase);
  __shared__ __align__(16) char lA[2][64 * 64];
  __shared__ __align__(16) char lB[2][64 * 64];
  f32x4 acc[2][2] = {};
  constexpr int NT = DIN / KS / 32;
  stage_tile<64>(xb, DIN * 2, lA[0]);
  stage_tile<64>(mb, DIN * 2, lB[0]);
  for (int t = 0; t < NT; ++t) {
    __syncthreads();
    if (t + 1 < NT) {
      stage_tile<64>(xb + (t + 1) * 64, DIN * 2, lA[(t + 1) & 1]);
      stage_tile<64>(mb + (t + 1) * 64, DIN * 2, lB[(t + 1) & 1]);
    }
    compute_tile<2>(lA[t & 1], lB[t & 1], acc);
  }
  const int lane = threadIdx.x & 63;
  const int wave = threadIdx.x >> 6;
  const int wr = wave >> 1, wc = wave & 1;
#pragma unroll
  for (int mi = 0; mi < 2; ++mi)
#pragma unroll
    for (int ni = 0; ni < 2; ++ni) {
      int c = nt * 64 + wc * 32 + ni * 16 + (lane & 15);
      int r0 = row0 + wr * 32 + mi * 16 + (lane >> 4) * 4;
#pragma unroll
      for (int j = 0; j < 4; ++j)
        zpart[((size_t)ksl * MTOT + r0 + j) * RANK + c] = acc[mi][ni][j];
    }
}

template <int KS>
__global__ void z_reduce_kernel(const float* __restrict__ zpart,
                                unsigned short* __restrict__ zbf) {
  const int n4 = MTOT * RANK / 4;
  int i = blockIdx.x * blockDim.x + threadIdx.x;
  if (i >= n4) return;
  float4 s = reinterpret_cast<const float4*>(zpart)[i];
#pragma unroll
  for (int k = 1; k < KS; ++k) {
    float4 v = reinterpret_cast<const float4*>(zpart)[(size_t)k * n4 + i];
    s.x += v.x; s.y += v.y; s.z += v.z; s.w += v.w;
  }
  ushort4 o;
  o.x = f2bf(s.x); o.y = f2bf(s.y); o.z = f2bf(s.z); o.w = f2bf(s.w);
  reinterpret_cast<ushort4*>(zbf)[i] = o;
}

// fallback (no split-K)
__global__ __launch_bounds__(256) void z_gemm_kernel(
    const unsigned short* __restrict__ xbf, const unsigned short* __restrict__ mbf,
    unsigned short* __restrict__ zbf) {
  int mt = blockIdx.x >> 1, nt = blockIdx.x & 1;
  int row0 = mt * 64;
  int batch = row0 >> 11;
  const char* xb = (const char*)(xbf + (size_t)row0 * DIN);
  const char* mb = (const char*)(mbf + ((size_t)batch * RANK + nt * 64) * DIN);
  __shared__ __align__(16) char lA[2][64 * 64];
  __shared__ __align__(16) char lB[2][64 * 64];
  f32x4 acc[2][2] = {};
  constexpr int NT = DIN / 32;
  stage_tile<64>(xb, DIN * 2, lA[0]);
  stage_tile<64>(mb, DIN * 2, lB[0]);
  for (int t = 0; t < NT; ++t) {
    __syncthreads();
    if (t + 1 < NT) {
      stage_tile<64>(xb + (t + 1) * 64, DIN * 2, lA[(t + 1) & 1]);
      stage_tile<64>(mb + (t + 1) * 64, DIN * 2, lB[(t + 1) & 1]);
    }
    compute_tile<2>(lA[t & 1], lB[t & 1], acc);
  }
  const int lane = threadIdx.x & 63;
  const int wave = threadIdx.x >> 6;
  const int wr = wave >> 1, wc = wave & 1;
#pragma unroll
  for (int mi = 0; mi < 2; ++mi)
#pragma unroll
    for (int ni = 0; ni < 2; ++ni) {
      int c = nt * 64 + wc * 32 + ni * 16 + (lane & 15);
      int r0 = row0 + wr * 32 + mi * 16 + (lane >> 4) * 4;
#pragma unroll
      for (int j = 0; j < 4; ++j)
        zbf[(size_t)(r0 + j) * RANK + c] = f2bf(acc[mi][ni][j]);
    }
}

// ---------------- main GEMM: 256x256, BK=64, 8 waves, pipelined 8-phase ----------------
// Phase q within a K-tile: q=(ks,mihalf); phase p issues ds_reads for phase p+1's
// fragments (reg ping-pong), then MFMA(p) on regs read last phase -> LDS reads
// overlap MFMA (compiler emits partial lgkmcnt). One s_barrier per phase.
// Stages: ph0: A(t+1)+B(t+1)h1 -> buf1; ph3: B(t+2)h0 -> buf0;
//         ph4: A(t+2)+B(t+2)h1 -> buf0; ph7: B(t+3)h0 -> buf1.
// vmcnt(0) at end of ph2 and ph6 only (drains stages >=2 phases old; cross-buffer
// reads happen at ph3-A/ph7-A, after drain+barrier). Region-disjointness of
// stage targets vs in-window reads verified per phase (see session notes).

struct MainCtx {
  const char* lds;
  int wr, wc, rsel, kgrp, xorv;
};

DEVI const bf16x8* lda_frag(const MainCtx& c, int d, int mi, int ks) {
  int col = ((ks * 64) + c.kgrp * 16) ^ c.xorv;
  return reinterpret_cast<const bf16x8*>(
      c.lds + d * 32768 + c.wr * 16384 + mi * 2048 + c.rsel * 128 + col);
}
DEVI const bf16x8* ldb_frag(const MainCtx& c, int d, int ni, int ks) {
  int col = ((ks * 64) + c.kgrp * 16) ^ c.xorv;
  return reinterpret_cast<const bf16x8*>(
      c.lds + 65536 + d * 32768 + (c.wc >> 1) * 16384 + (c.wc & 1) * 8192 +
      ni * 2048 + c.rsel * 128 + col);
}

template <int PH>
struct PhaseCfg {
  static constexpr int q = PH & 3;
  static constexpr int mih = q & 1;
  static constexpr int aCur = PH & 1;
  static constexpr int aNxt = (PH + 1) & 1;
  static constexpr int bCur = (PH >> 1) & 1;
  static constexpr int nq = (PH + 1) & 3;
  static constexpr int nbuf = ((PH + 1) >> 2) & 1;  // ph7 wraps to buf0
  static constexpr int nks = nq >> 1;
  static constexpr int nmih = nq & 1;
  static constexpr bool rdB = (PH & 1) == 1;        // odd phases read next B-set
  static constexpr int bNxt = ((PH + 1) >> 1) & 1;
};

template <int PH, bool VM0, class STG>
DEVI void phase(const MainCtx& c, f32x4 (&acc)[8][4], bf16x8 (&aS)[2][4],
                bf16x8 (&bS)[2][4], STG&& stg) {
  using P = PhaseCfg<PH>;
  // ds_reads for NEXT phase's fragments (overlap with this phase's MFMA)
#pragma unroll
  for (int m = 0; m < 4; ++m)
    aS[P::aNxt][m] = *lda_frag(c, P::nbuf, P::nmih * 4 + m, P::nks);
  if constexpr (P::rdB) {
#pragma unroll
    for (int ni = 0; ni < 4; ++ni)
      bS[P::bNxt][ni] = *ldb_frag(c, P::nbuf, ni, P::nks);
  }
  stg();  // issue global_load_lds prefetch for future tiles
  __builtin_amdgcn_s_setprio(1);
#pragma unroll
  for (int m = 0; m < 4; ++m)
#pragma unroll
    for (int ni = 0; ni < 4; ++ni)
      acc[P::mih * 4 + m][ni] = __builtin_amdgcn_mfma_f32_16x16x32_bf16(
          aS[P::aCur][m], bS[P::bCur][ni], acc[P::mih * 4 + m][ni], 0, 0, 0);
  __builtin_amdgcn_s_setprio(0);
  if constexpr (VM0)
    asm volatile("s_waitcnt vmcnt(0)" ::: "memory");
  else
    asm volatile("" ::: "memory");
  __builtin_amdgcn_s_barrier();
}

__global__ __launch_bounds__(512, 2) void main_gemm_8p(
    const unsigned short* __restrict__ xbf, const unsigned short* __restrict__ wlbf,
    const unsigned short* __restrict__ zbf, const unsigned short* __restrict__ wobf,
    const float* __restrict__ b_lin, float* __restrict__ out) {
  __shared__ __align__(16) char lds[131072];

  const int tid = threadIdx.x;
  const int lane = tid & 63, wave = tid >> 6;

  int bid = blockIdx.x;                   // 512 blocks, 512%8==0
  int swz = (bid & 7) * 64 + (bid >> 3);  // bijective XCD swizzle
  int mt = swz >> 4, nt = swz & 15;
  const int row0 = mt * 256, col0 = nt * 256;

  const char* xb = (const char*)(xbf + (size_t)row0 * DIN);
  const char* wb = (const char*)(wlbf + (size_t)col0 * DIN);
  const char* zb = (const char*)(zbf + (size_t)row0 * RANK);
  const char* ob = (const char*)(wobf + (size_t)col0 * RANK);

  // staging lane constants (pre-swizzled source; linear LDS dest — rule 21)
  const int srow8 = lane >> 3;
  const int scolS = ((lane & 7) ^ srow8) << 4;
  const int chunk0 = wave * 2;

  auto stage = [&](const char* gbase, int ld, int ldsOff) {
    gload16(gbase + (size_t)(chunk0 * 8 + srow8) * ld + scolS,
            (void*)&lds[ldsOff + chunk0 * 1024]);
    gload16(gbase + (size_t)(chunk0 * 8 + 8 + srow8) * ld + scolS,
            (void*)&lds[ldsOff + chunk0 * 1024 + 1024]);
  };
  auto stageA = [&](int k, int h, int d) {
    const char* g; int ld;
    if (k < 64) { g = xb + (size_t)h * 128 * (DIN * 2) + (size_t)k * 128; ld = DIN * 2; }
    else        { g = zb + (size_t)h * 128 * (RANK * 2) + (size_t)(k - 64) * 128; ld = RANK * 2; }
    stage(g, ld, d * 32768 + h * 16384);
  };
  auto stageB = [&](int k, int h, int d) {
    const char* g; int ld;
    if (k < 64) { g = wb + (size_t)h * 128 * (DIN * 2) + (size_t)k * 128; ld = DIN * 2; }
    else        { g = ob + (size_t)h * 128 * (RANK * 2) + (size_t)(k - 64) * 128; ld = RANK * 2; }
    stage(g, ld, 65536 + d * 32768 + h * 16384);
  };

  MainCtx c{lds, wave >> 2, wave & 3, lane & 15, lane >> 4, (lane & 7) << 4};

  f32x4 acc[8][4] = {};
  bf16x8 aS[2][4], bS[2][4];

  // prologue: tile0 A+B -> buf0 (8 loads), B(1)h0 -> buf1 (2, stays in flight)
  stageA(0, 0, 0); stageA(0, 1, 0);
  stageB(0, 0, 0); stageB(0, 1, 0);
  stageB(1, 0, 1);
  asm volatile("s_waitcnt vmcnt(2)" ::: "memory");
  __builtin_amdgcn_s_barrier();
#pragma unroll
  for (int m = 0; m < 4; ++m) aS[0][m] = *lda_frag(c, 0, m, 0);
#pragma unroll
  for (int ni = 0; ni < 4; ++ni) bS[0][ni] = *ldb_frag(c, 0, ni, 0);

  constexpr int NKT = 66;  // 64 (x/wl) + 2 (z/wo)
  for (int j = 0; j < NKT / 2; ++j) {
    int t = 2 * j;
    int kA1 = (t + 1 < NKT - 1) ? t + 1 : NKT - 1;
    int kN2 = (t + 2 < NKT - 1) ? t + 2 : NKT - 1;
    int kB3 = (t + 3 < NKT - 1) ? t + 3 : NKT - 1;
    phase<0, false>(c, acc, aS, bS,
                    [&] { stageA(kA1, 0, 1); stageA(kA1, 1, 1); stageB(kA1, 1, 1); });
    phase<1, false>(c, acc, aS, bS, [&] {});
    phase<2, true >(c, acc, aS, bS, [&] {});
    phase<3, false>(c, acc, aS, bS, [&] { stageB(kN2, 0, 0); });
    phase<4, false>(c, acc, aS, bS,
                    [&] { stageA(kN2, 0, 0); stageA(kN2, 1, 0); stageB(kN2, 1, 0); });
    phase<5, false>(c, acc, aS, bS, [&] {});
    phase<6, true >(c, acc, aS, bS, [&] {});
    phase<7, false>(c, acc, aS, bS, [&] { stageB(kB3, 0, 1); });
  }
  asm volatile("s_waitcnt vmcnt(0)" ::: "memory");

  // epilogue
  const int wr = wave >> 2, wc = wave & 3;
  const int rbase = row0 + wr * 128 + (lane >> 4) * 4;
  const int cbase = col0 + wc * 64 + (lane & 15);
#pragma unroll
  for (int mi = 0; mi < 8; ++mi)
#pragma unroll
    for (int ni = 0; ni < 4; ++ni) {
      int cc = cbase + ni * 16;
      float bv = b_lin[cc];
      int r = rbase + mi * 16;
#pragma unroll
      for (int j2 = 0; j2 < 4; ++j2)
        out[(size_t)(r + j2) * DOUT + cc] = acc[mi][ni][j2] + bv;
    }
}

// ---------------- launch ----------------

extern "C" void kernel_launch(void* const* d_in, const int* in_sizes, int n_in,
                              void* d_out, int out_size, void* d_ws, size_t ws_size,
                              hipStream_t stream) {
  const float* x = (const float*)d_in[0];
  const float* log_lr = (const float*)d_in[1];
  const float* state = (const float*)d_in[2];
  const float* w_bsp = (const float*)d_in[4];
  const float* w_out = (const float*)d_in[5];
  const float* w_lin = (const float*)d_in[6];
  const float* b_lin = (const float*)d_in[7];
  float* out = (float*)d_out;

  unsigned short* xbf = (unsigned short*)d_ws;              // 67108864 B
  unsigned short* wlbf = xbf + (size_t)MTOT * DIN;          // 33554432 B
  unsigned short* wobf = wlbf + (size_t)DOUT * DIN;         // 1048576 B
  unsigned short* mbf = wobf + (size_t)DOUT * RANK;         // 4194304 B
  unsigned short* zbf = mbf + (size_t)BS * RANK * DIN;      // 2097152 B
  float* zpart = (float*)(zbf + (size_t)MTOT * RANK);       // 16777216 B
  const size_t need_split = 108003328 + 16777216;

  cast_bf16_kernel<<<2048, 256, 0, stream>>>(x, xbf, MTOT * DIN / 4);
  cast_bf16_kernel<<<2048, 256, 0, stream>>>(w_lin, wlbf, DOUT * DIN / 4);
  cast_bf16_kernel<<<512, 256, 0, stream>>>(w_out, wobf, DOUT * RANK / 4);
  prep_m_kernel<<<2048, 256, 0, stream>>>(log_lr, state, w_bsp, mbf);

  if (ws_size >= need_split) {
    z_gemm_splitk<4><<<1024, 256, 0, stream>>>(xbf, mbf, zpart);
    z_reduce_kernel<4><<<1024, 256, 0, stream>>>(zpart, zbf);
  } else {
    z_gemm_kernel<<<256, 256, 0, stream>>>(xbf, mbf, zbf);
  }

  main_gemm_8p<<<512, 512, 0, stream>>>(xbf, wlbf, zbf, wobf, b_lin, out);
}